// Round 4
// baseline (251.564 us; speedup 1.0000x reference)
//
#include <hip/hip_runtime.h>
#include <hip/hip_bf16.h>

typedef unsigned short u16;
typedef float f32x4 __attribute__((ext_vector_type(4)));
typedef short s16x8 __attribute__((ext_vector_type(8)));

#define NB 4
#define NN 20000
#define NE 320000
#define ROWS (NB*NN)          // 80000
#define NBLK 313              // gate blocks per batch (313*4 waves >= 1250 tiles)
#define SLOTCAP 64            // max degree capacity (Poisson(16): P(>64) ~ 1e-20)
#define XTBLK 5000            // xt role blocks in setup
#define FSBLK 1250            // fillslots role blocks (NE/256)
#define AGGB 5000             // agg role blocks ((NN+3)/4); prep blocks appended after
#define PREPB 6               // weight-prep role blocks (in agg_kernel)

__device__ __forceinline__ float b2f(u16 u){
  union{unsigned int i; float f;} v; v.i = ((unsigned int)u)<<16; return v.f;
}
__device__ __forceinline__ u16 f2b(float f){
  __hip_bfloat16 h = __float2bfloat16(f);
  return __builtin_bit_cast(u16, h);
}

// fast sigmoid/tanh: v_rcp + v_exp (rel err ~1e-6; tolerance budget is bf16-level)
__device__ __forceinline__ float fsig(float x){
  return __builtin_amdgcn_rcpf(1.f + __expf(-x));
}
__device__ __forceinline__ float ftanh(float x){
  // 1 - 2/(e^{2x}+1): x->+inf => 1, x->-inf => -1 (no NaN at saturation)
  return 1.f - 2.f*__builtin_amdgcn_rcpf(__expf(2.f*x) + 1.f);
}

// ---------------- K1: setup — slotted edge scatter FIRST (blocks 0..1249),
//                   xt transpose after. ONE atomic per edge (cursor only;
//                   deg is recomputed from slots by degsum_kernel). ----------
__global__ void __launch_bounds__(256, 8) setup_kernel(
    const float* __restrict__ x, ushort4* __restrict__ xt4,
    const int* __restrict__ ei, const float* __restrict__ ew,
    int* __restrict__ cursor, int2* __restrict__ slots){
  int bid = blockIdx.x;
  if(bid < FSBLK){
    // -------- edge scatter: 1250*256 == NE exactly --------
    int e = bid*256 + threadIdx.x;
    int s = ei[e], d = ei[NE + e];
    float w = ew[e];
    int p = atomicAdd(&cursor[d], 1);
    if(p < SLOTCAP){
      int2 ent; ent.x = s; ent.y = __float_as_int(w);
      slots[d*SLOTCAP + p] = ent;
    }
  } else {
    // -------- xt transpose: pure streaming, backfills behind scatter --------
    int t = (bid - FSBLK)*256 + threadIdx.x;   // 0 .. NB*NN*16-1
    int b = t / (NN*16);
    int rem = t - b*(NN*16);
    int n = rem >> 4;
    int c4 = rem & 15;
    float4 v = reinterpret_cast<const float4*>(x)[t];
    ushort4 o; o.x=f2b(v.x); o.y=f2b(v.y); o.z=f2b(v.z); o.w=f2b(v.w);
    xt4[(size_t)n*64 + b*16 + c4] = o;
  }
}

__device__ __forceinline__ float dinvf(float d){
  return (d > 0.f) ? rsqrtf(fmaxf(d, 1e-12f)) : 0.f;
}

// ---------------- K1b: degsum — dinv[n] = rsqrt(sum of stored weights).
//                   Quarter-wave per node; slots are L2/L3-hot. -------------
__global__ void __launch_bounds__(256, 8) degsum_kernel(
    const int* __restrict__ cursor, const int2* __restrict__ slots,
    float* __restrict__ dinv){
  int node = (blockIdx.x*256 + threadIdx.x) >> 4;
  int sub  = threadIdx.x & 15;
  if(node >= NN) return;
  int cnt = min(cursor[node], SLOTCAP);
  const int2* sl = slots + (size_t)node*SLOTCAP;
  float s = 0.f;
  for(int j=sub; j<cnt; j+=16) s += __int_as_float(sl[j].y);
  s += __shfl_xor(s, 1, 16);
  s += __shfl_xor(s, 2, 16);
  s += __shfl_xor(s, 4, 16);
  s += __shfl_xor(s, 8, 16);
  if(sub == 0) dinv[node] = dinvf(s);
}

// ---------------- K2: per-node aggregation (wave per node, 4x unrolled) +
//                   weight-prep role in 6 tail blocks. ----------------------
__global__ void agg_kernel(const ushort4* __restrict__ xt4, const float* __restrict__ dinv,
                           const int* __restrict__ cursor, const int2* __restrict__ slots,
                           u16* __restrict__ agg,
                           const float* Wz, const float* bz, const float* Lz, const float* lbz,
                           const float* Wr, const float* br, const float* Lr, const float* lbr,
                           const float* Wh, const float* bh, const float* Lh, const float* lbh,
                           int4* __restrict__ wfrag, float* __restrict__ cvec){
  __shared__ __align__(16) float Pl[4096];   // used only by prep role; 16KB keeps
                                             // agg at its wave-cap occupancy (8 blk/CU)
  if(blockIdx.x >= AGGB){
    // -------- weight prep: Pr = W @ L_top (fp32, ascending-k order — bit-identical) --
    int m = blockIdx.x - AGGB;       // 0..5
    int g = m >> 1, half = m & 1;
    const float* W  = (g==0)?Wz:(g==1)?Wr:Wh;
    const float* L  = (g==0)?Lz:(g==1)?Lr:Lh;
    const float* bb = (g==0)?bz:(g==1)?br:bh;
    const float* lb = (g==0)?lbz:(g==1)?lbr:lbh;
    int t = threadIdx.x;
    if(half == 0){
      // stage L_top (rows 0..63 of L) into Pl
      for(int i=t; i<1024; i+=256)
        reinterpret_cast<float4*>(Pl)[i] = reinterpret_cast<const float4*>(L)[i];
      __syncthreads();
      // thread t owns row i = t>>2, cols j0..j0+15; W streamed 4 k at a time
      int i = t >> 2, j0 = (t & 3) * 16;
      float acc[16];
      #pragma unroll
      for(int q=0;q<16;q++) acc[q] = 0.f;
      for(int kb=0; kb<16; kb++){
        float4 w4 = *reinterpret_cast<const float4*>(W + i*64 + kb*4);
        const float* l0 = Pl + (kb*4)*64 + j0;
        #pragma unroll
        for(int q=0;q<16;q++) acc[q] += w4.x * l0[q];
        #pragma unroll
        for(int q=0;q<16;q++) acc[q] += w4.y * l0[64+q];
        #pragma unroll
        for(int q=0;q<16;q++) acc[q] += w4.z * l0[128+q];
        #pragma unroll
        for(int q=0;q<16;q++) acc[q] += w4.w * l0[192+q];
      }
      // bias-through-L (needs L_top still live in Pl)
      float cv = 0.f;
      if(t < 64){
        cv = lb[t];
        for(int k=0;k<64;k++) cv += bb[k]*Pl[k*64+t];
      }
      __syncthreads();
      // overwrite Pl with the product
      #pragma unroll
      for(int q=0;q<16;q++) Pl[i*64 + j0 + q] = acc[q];
      if(t < 64) cvec[g*64 + t] = cv;
      __syncthreads();
    } else {
      // H-half of L used directly
      for(int i=t; i<1024; i+=256)
        reinterpret_cast<float4*>(Pl)[i] = reinterpret_cast<const float4*>(L + 4096)[i];
      __syncthreads();
    }
    // pack to MFMA B-fragment layout (bf16)
    for(int it=t; it<512; it+=256){
      int l  = it & 63;
      int rl = it >> 6;          // s*4 + tt
      int s  = rl >> 2, tt = rl & 3;
      int k0 = s*32 + (l>>4)*8;
      int n  = tt*16 + (l&15);
      union { u16 v[8]; int4 q4; } tmp;
      #pragma unroll
      for(int j=0;j<8;j++) tmp.v[j] = f2b(Pl[(k0+j)*64 + n]);
      wfrag[m*512 + it] = tmp.q4;
    }
    return;
  }
  int wave = (blockIdx.x*blockDim.x + threadIdx.x) >> 6;
  int lane = threadIdx.x & 63;
  if(wave >= NN) return;
  int cnt = min(cursor[wave], SLOTCAP);
  float dn = dinv[wave];
  const int2* sl = slots + (size_t)wave*SLOTCAP;
  float a0=0.f, a1=0.f, a2=0.f, a3=0.f;
  int j = 0;
  for(; j+3 < cnt; j+=4){
    int2 ea = sl[j],   eb = sl[j+1];
    int2 ec = sl[j+2], ed = sl[j+3];
    ushort4 va = xt4[(size_t)ea.x*64 + lane];
    ushort4 vb = xt4[(size_t)eb.x*64 + lane];
    ushort4 vc = xt4[(size_t)ec.x*64 + lane];
    ushort4 vd = xt4[(size_t)ed.x*64 + lane];
    float wa = dinv[ea.x] * __int_as_float(ea.y) * dn;
    float wb = dinv[eb.x] * __int_as_float(eb.y) * dn;
    float wc = dinv[ec.x] * __int_as_float(ec.y) * dn;
    float wd = dinv[ed.x] * __int_as_float(ed.y) * dn;
    a0 += wa*b2f(va.x) + wb*b2f(vb.x) + wc*b2f(vc.x) + wd*b2f(vd.x);
    a1 += wa*b2f(va.y) + wb*b2f(vb.y) + wc*b2f(vc.y) + wd*b2f(vd.y);
    a2 += wa*b2f(va.z) + wb*b2f(vb.z) + wc*b2f(vc.z) + wd*b2f(vd.z);
    a3 += wa*b2f(va.w) + wb*b2f(vb.w) + wc*b2f(vc.w) + wd*b2f(vd.w);
  }
  for(; j < cnt; j++){
    int2 e = sl[j];
    float w = dinv[e.x] * __int_as_float(e.y) * dn;
    ushort4 v = xt4[(size_t)e.x*64 + lane];
    a0 += w * b2f(v.x);
    a1 += w * b2f(v.y);
    a2 += w * b2f(v.z);
    a3 += w * b2f(v.w);
  }
  int b = lane >> 4, c4 = lane & 15;
  ushort4 o; o.x=f2b(a0); o.y=f2b(a1); o.z=f2b(a2); o.w=f2b(a3);
  reinterpret_cast<ushort4*>(agg)[((size_t)b*NN + wave)*16 + c4] = o;
}

// ---------------- K3: fused GRU gate + pool partials (MFMA) + inline head
//                   (last-block finalize; head_kernel dispatch eliminated) --
#define LDW(m,s,t) __builtin_bit_cast(s16x8, wfrag[((m)*8+(s)*4+(t))*64 + lane])

__global__ void __launch_bounds__(256, 4) gate_kernel(
    const u16* __restrict__ agg, const float* __restrict__ H,
    const int4* __restrict__ wfrag, const float* __restrict__ cvec,
    const float* __restrict__ gate_w, const float* __restrict__ gate_b,
    float* __restrict__ Hnew,
    float* __restrict__ yacc, float* __restrict__ dacc, unsigned int* __restrict__ done,
    const float* __restrict__ W1, const float* __restrict__ b1,
    const float* __restrict__ W2, const float* __restrict__ b2,
    float* __restrict__ out)
{
  __shared__ __align__(16) u16 rlds[4][1152];       // per-wave R tile, 16 rows x 72 (padded)
  __shared__ float ylds[4][64];                     // per-wave pool partials
  __shared__ float dlds[4];
  __shared__ int lastflag;
  __shared__ float yv_s[4][64];
  __shared__ float hid_s[4][64];

  const int warp = threadIdx.x >> 6, lane = threadIdx.x & 63;
  const int mrow = lane & 15, quad = lane >> 4;
  const int bat = blockIdx.x / NBLK;
  const int blk = blockIdx.x % NBLK;
  const int tin = blk*4 + warp;           // tile within batch, 0..1251
  const bool valid = (tin < 1250);
  const int r0 = bat*NN + tin*16;         // global row (guarded by valid)

  float czv[4], crv[4], chv[4], gwv[4];
  #pragma unroll
  for(int t=0;t<4;t++){
    czv[t] = cvec[t*16+mrow];
    crv[t] = cvec[64 + t*16+mrow];
    chv[t] = cvec[128 + t*16+mrow];
    gwv[t] = gate_w[t*16+mrow];
  }
  const float gb = gate_b[0];

  f32x4 Zc[4], Rc[4], Hc[4];
  union { f32x4 v4[2]; float f[8]; } u0, u1;
  if(valid){
    const int4* ap = reinterpret_cast<const int4*>(agg + (size_t)(r0+mrow)*64);
    s16x8 a0 = __builtin_bit_cast(s16x8, ap[quad]);
    s16x8 a1 = __builtin_bit_cast(s16x8, ap[4+quad]);

    const float* Hrow = H + (size_t)(r0+mrow)*64;
    u0.v4[0] = *reinterpret_cast<const f32x4*>(Hrow + quad*8);
    u0.v4[1] = *reinterpret_cast<const f32x4*>(Hrow + quad*8 + 4);
    u1.v4[0] = *reinterpret_cast<const f32x4*>(Hrow + 32 + quad*8);
    u1.v4[1] = *reinterpret_cast<const f32x4*>(Hrow + 32 + quad*8 + 4);
    s16x8 h0, h1;
    #pragma unroll
    for(int j=0;j<8;j++){
      h0[j] = (short)f2b(u0.f[j]);
      h1[j] = (short)f2b(u1.f[j]);
    }

    #pragma unroll
    for(int t=0;t<4;t++){
      f32x4 acc = {0.f,0.f,0.f,0.f};
      acc = __builtin_amdgcn_mfma_f32_16x16x32_bf16(a0, LDW(0,0,t), acc, 0,0,0);
      acc = __builtin_amdgcn_mfma_f32_16x16x32_bf16(a1, LDW(0,1,t), acc, 0,0,0);
      acc = __builtin_amdgcn_mfma_f32_16x16x32_bf16(h0, LDW(1,0,t), acc, 0,0,0);
      acc = __builtin_amdgcn_mfma_f32_16x16x32_bf16(h1, LDW(1,1,t), acc, 0,0,0);
      Zc[t] = acc;
      f32x4 ar = {0.f,0.f,0.f,0.f};
      ar = __builtin_amdgcn_mfma_f32_16x16x32_bf16(a0, LDW(2,0,t), ar, 0,0,0);
      ar = __builtin_amdgcn_mfma_f32_16x16x32_bf16(a1, LDW(2,1,t), ar, 0,0,0);
      ar = __builtin_amdgcn_mfma_f32_16x16x32_bf16(h0, LDW(3,0,t), ar, 0,0,0);
      ar = __builtin_amdgcn_mfma_f32_16x16x32_bf16(h1, LDW(3,1,t), ar, 0,0,0);
      Rc[t] = ar;
      f32x4 ah = {0.f,0.f,0.f,0.f};
      ah = __builtin_amdgcn_mfma_f32_16x16x32_bf16(a0, LDW(4,0,t), ah, 0,0,0);
      ah = __builtin_amdgcn_mfma_f32_16x16x32_bf16(a1, LDW(4,1,t), ah, 0,0,0);
      Hc[t] = ah;
    }

    // sigmoid(R) -> LDS (C-layout write); per-warp buffer, in-wave ordering.
    #pragma unroll
    for(int t=0;t<4;t++){
      #pragma unroll
      for(int i=0;i<4;i++){
        float r = fsig(Rc[t][i] + crv[t]);
        rlds[warp][(quad*4+i)*72 + t*16 + mrow] = f2b(r);
      }
    }
    const u16* rp = &rlds[warp][mrow*72 + quad*8];
    int4 rv0 = *reinterpret_cast<const int4*>(rp);
    int4 rv1 = *reinterpret_cast<const int4*>(rp + 32);
    const u16* rv0p = reinterpret_cast<const u16*>(&rv0);
    const u16* rv1p = reinterpret_cast<const u16*>(&rv1);
    s16x8 hr0, hr1;
    #pragma unroll
    for(int j=0;j<8;j++){
      hr0[j] = (short)f2b(u0.f[j] * b2f(rv0p[j]));
      hr1[j] = (short)f2b(u1.f[j] * b2f(rv1p[j]));
    }
    #pragma unroll
    for(int t=0;t<4;t++){
      Hc[t] = __builtin_amdgcn_mfma_f32_16x16x32_bf16(hr0, LDW(5,0,t), Hc[t], 0,0,0);
      Hc[t] = __builtin_amdgcn_mfma_f32_16x16x32_bf16(hr1, LDW(5,1,t), Hc[t], 0,0,0);
    }

    // epilogue: Z, Ht, H_new, gate logits, pool partials
    float hnv[4][4];
    float ga[4] = {0.f,0.f,0.f,0.f};
    #pragma unroll
    for(int t=0;t<4;t++){
      #pragma unroll
      for(int i=0;i<4;i++){
        int row = r0 + quad*4 + i, col = t*16 + mrow;
        float z  = fsig(Zc[t][i] + czv[t]);
        float ht = ftanh(Hc[t][i] + chv[t]);
        float hv = H[(size_t)row*64 + col];
        float hn = z*hv + (1.f - z)*ht;
        Hnew[(size_t)row*64 + col] = hn;
        hnv[t][i] = hn;
        ga[i] += hn * gwv[t];
      }
    }
    #pragma unroll
    for(int i=0;i<4;i++){
      float v = ga[i];
      v += __shfl_xor(v, 1, 64);
      v += __shfl_xor(v, 2, 64);
      v += __shfl_xor(v, 4, 64);
      v += __shfl_xor(v, 8, 64);
      ga[i] = v;
    }
    float e_[4]; float dsum = 0.f;
    #pragma unroll
    for(int i=0;i<4;i++){ e_[i] = __expf(ga[i] + gb); dsum += e_[i]; }
    #pragma unroll
    for(int t=0;t<4;t++){
      float s = 0.f;
      #pragma unroll
      for(int i=0;i<4;i++) s += e_[i]*hnv[t][i];
      s += __shfl_xor(s, 16, 64);
      s += __shfl_xor(s, 32, 64);
      if(lane < 16) ylds[warp][t*16 + mrow] = s;
    }
    dsum += __shfl_xor(dsum, 16, 64);
    dsum += __shfl_xor(dsum, 32, 64);
    if(lane == 0) dlds[warp] = dsum;
  } else {
    if(lane < 16){
      #pragma unroll
      for(int t=0;t<4;t++) ylds[warp][t*16 + mrow] = 0.f;
    }
    if(lane == 0) dlds[warp] = 0.f;
  }
  __syncthreads();
  int t = threadIdx.x;
  if(t < 64){
    float s = ylds[0][t] + ylds[1][t] + ylds[2][t] + ylds[3][t];
    atomicAdd(&yacc[bat*64 + t], s);
  }
  if(t == 64) atomicAdd(&dacc[bat], dlds[0] + dlds[1] + dlds[2] + dlds[3]);
  // barrier drains each thread's memory ops (vmcnt(0) before s_barrier) ->
  // this block's atomics are device-visible before the ticket below.
  __syncthreads();
  if(t == 0){
    __threadfence();
    unsigned int old = atomicAdd(done, 1u);
    lastflag = (old == (unsigned int)(NB*NBLK - 1));
  }
  __syncthreads();
  if(lastflag){
    // ---- inline head: only the last block reaches here; all pool atomics done ----
    __threadfence();
    int b = t >> 6, dcol = t & 63;
    float dv   = __hip_atomic_load(&dacc[b], __ATOMIC_RELAXED, __HIP_MEMORY_SCOPE_AGENT);
    float yval = __hip_atomic_load(&yacc[b*64 + dcol], __ATOMIC_RELAXED, __HIP_MEMORY_SCOPE_AGENT);
    yv_s[b][dcol] = yval / dv;
    __syncthreads();
    float acc = b1[dcol];
    #pragma unroll 4
    for(int k=0;k<64;k++) acc += yv_s[b][k] * W1[k*64 + dcol];
    hid_s[b][dcol] = fmaxf(acc, 0.f);
    __syncthreads();
    if(t < 128){
      int bb = t >> 5, c = t & 31;
      float a2 = b2[c];
      #pragma unroll 4
      for(int d2=0; d2<64; d2++) a2 += hid_s[bb][d2] * W2[d2*32 + c];
      out[bb*32 + c] = a2;
    }
  }
}

// ---------------- launch ----------------
extern "C" void kernel_launch(void* const* d_in, const int* in_sizes, int n_in,
                              void* d_out, int out_size, void* d_ws, size_t ws_size,
                              hipStream_t stream) {
  const float* x   = (const float*)d_in[0];
  const int*   ei  = (const int*)d_in[1];
  const float* ew  = (const float*)d_in[2];
  const float* H   = (const float*)d_in[3];
  const float* Wz = (const float*)d_in[4],  *bz = (const float*)d_in[5];
  const float* Wr = (const float*)d_in[6],  *br = (const float*)d_in[7];
  const float* Wh = (const float*)d_in[8],  *bh = (const float*)d_in[9];
  const float* Lz = (const float*)d_in[10], *lbz = (const float*)d_in[11];
  const float* Lr = (const float*)d_in[12], *lbr = (const float*)d_in[13];
  const float* Lh = (const float*)d_in[14], *lbh = (const float*)d_in[15];
  const float* gw = (const float*)d_in[16], *gbp = (const float*)d_in[17];
  const float* W1 = (const float*)d_in[18], *b1 = (const float*)d_in[19];
  const float* W2 = (const float*)d_in[20], *b2 = (const float*)d_in[21];

  float* y_out    = (float*)d_out;
  float* Hnew_out = (float*)d_out + 128;

  char* ws = (char*)d_ws;
  size_t off = 0;
  auto alloc = [&](size_t bytes)->char*{
    off = (off + 255) & ~(size_t)255;
    char* p = ws + off; off += bytes; return p;
  };
  // zero region: cursor (80000B) + yacc (1024B) + dacc (16B) + done (4B), one memset
  char*    zr       = alloc(NN*4 + 2048);
  int*     cursor   = (int*)zr;
  float*   yacc     = (float*)(zr + NN*4);          // 80000 % 16 == 0
  float*   dacc     = (float*)(zr + NN*4 + 1024);
  unsigned int* done= (unsigned int*)(zr + NN*4 + 1024 + 16);
  float*   dinv     = (float*)alloc(NN*4);
  int2*    slots    = (int2*) alloc((size_t)NN*SLOTCAP*8);
  ushort4* xt4      = (ushort4*)alloc((size_t)NN*256*2);
  u16*     agg      = (u16*)  alloc((size_t)ROWS*64*2);
  int4*    wfrag    = (int4*) alloc(3072*16);
  float*   cvec     = (float*)alloc(192*4);
  (void)ws_size; (void)n_in; (void)in_sizes; (void)out_size;

  hipMemsetAsync(zr, 0, NN*4 + 1024 + 16 + 4, stream);

  setup_kernel<<<FSBLK + XTBLK, 256, 0, stream>>>(
      x, xt4, ei, ew, cursor, slots);
  degsum_kernel<<<FSBLK, 256, 0, stream>>>(cursor, slots, dinv);
  agg_kernel<<<AGGB + PREPB, 256, 0, stream>>>(
      xt4, dinv, cursor, slots, agg,
      Wz,bz,Lz,lbz, Wr,br,Lr,lbr, Wh,bh,Lh,lbh, wfrag, cvec);
  gate_kernel<<<NB*NBLK, 256, 0, stream>>>(
      agg, H, wfrag, cvec, gw, gbp, Hnew_out,
      yacc, dacc, done, W1, b1, W2, b2, y_out);
}

// Round 5
// 212.802 us; speedup vs baseline: 1.1822x; 1.1822x over previous
//
#include <hip/hip_runtime.h>
#include <hip/hip_bf16.h>

typedef unsigned short u16;
typedef float f32x4 __attribute__((ext_vector_type(4)));
typedef short s16x8 __attribute__((ext_vector_type(8)));

#define NB 4
#define NN 20000
#define NE 320000
#define ROWS (NB*NN)          // 80000
#define NBLK 313              // gate blocks per batch (313*4 waves >= 1250 tiles)
#define SLOTCAP 64            // max degree capacity (Poisson(16): P(>64) ~ 1e-20)
#define XTBLK 5000            // xt role blocks in setup
#define FSBLK 1250            // fillslots role blocks (NE/256)
#define AGGB 5000             // agg role blocks ((NN+3)/4); prep blocks appended after
#define PREPB 6               // weight-prep role blocks (in agg_kernel)

__device__ __forceinline__ float b2f(u16 u){
  union{unsigned int i; float f;} v; v.i = ((unsigned int)u)<<16; return v.f;
}
__device__ __forceinline__ u16 f2b(float f){
  __hip_bfloat16 h = __float2bfloat16(f);
  return __builtin_bit_cast(u16, h);
}

// fast sigmoid/tanh: v_rcp + v_exp (rel err ~1e-6; tolerance budget is bf16-level)
__device__ __forceinline__ float fsig(float x){
  return __builtin_amdgcn_rcpf(1.f + __expf(-x));
}
__device__ __forceinline__ float ftanh(float x){
  // 1 - 2/(e^{2x}+1): x->+inf => 1, x->-inf => -1 (no NaN at saturation)
  return 1.f - 2.f*__builtin_amdgcn_rcpf(__expf(2.f*x) + 1.f);
}

// ---------------- K1: setup — slotted edge scatter FIRST (blocks 0..1249),
//                   xt transpose after. ONE atomic per edge (cursor only;
//                   deg is recomputed from slots by degsum_kernel). ----------
__global__ void __launch_bounds__(256, 8) setup_kernel(
    const float* __restrict__ x, ushort4* __restrict__ xt4,
    const int* __restrict__ ei, const float* __restrict__ ew,
    int* __restrict__ cursor, int2* __restrict__ slots){
  int bid = blockIdx.x;
  if(bid < FSBLK){
    // -------- edge scatter: 1250*256 == NE exactly --------
    int e = bid*256 + threadIdx.x;
    int s = ei[e], d = ei[NE + e];
    float w = ew[e];
    int p = atomicAdd(&cursor[d], 1);
    if(p < SLOTCAP){
      int2 ent; ent.x = s; ent.y = __float_as_int(w);
      slots[d*SLOTCAP + p] = ent;
    }
  } else {
    // -------- xt transpose: pure streaming, backfills behind scatter --------
    int t = (bid - FSBLK)*256 + threadIdx.x;   // 0 .. NB*NN*16-1
    int b = t / (NN*16);
    int rem = t - b*(NN*16);
    int n = rem >> 4;
    int c4 = rem & 15;
    float4 v = reinterpret_cast<const float4*>(x)[t];
    ushort4 o; o.x=f2b(v.x); o.y=f2b(v.y); o.z=f2b(v.z); o.w=f2b(v.w);
    xt4[(size_t)n*64 + b*16 + c4] = o;
  }
}

__device__ __forceinline__ float dinvf(float d){
  return (d > 0.f) ? rsqrtf(fmaxf(d, 1e-12f)) : 0.f;
}

// ---------------- K1b: degsum — dinv[n] = rsqrt(sum of stored weights).
//                   Quarter-wave per node; slots are L2/L3-hot. -------------
__global__ void __launch_bounds__(256, 8) degsum_kernel(
    const int* __restrict__ cursor, const int2* __restrict__ slots,
    float* __restrict__ dinv){
  int node = (blockIdx.x*256 + threadIdx.x) >> 4;
  int sub  = threadIdx.x & 15;
  if(node >= NN) return;
  int cnt = min(cursor[node], SLOTCAP);
  const int2* sl = slots + (size_t)node*SLOTCAP;
  float s = 0.f;
  for(int j=sub; j<cnt; j+=16) s += __int_as_float(sl[j].y);
  s += __shfl_xor(s, 1, 16);
  s += __shfl_xor(s, 2, 16);
  s += __shfl_xor(s, 4, 16);
  s += __shfl_xor(s, 8, 16);
  if(sub == 0) dinv[node] = dinvf(s);
}

// ---------------- K2: per-node aggregation (wave per node, 4x unrolled) +
//                   weight-prep role in 6 tail blocks. ----------------------
__global__ void agg_kernel(const ushort4* __restrict__ xt4, const float* __restrict__ dinv,
                           const int* __restrict__ cursor, const int2* __restrict__ slots,
                           u16* __restrict__ agg,
                           const float* Wz, const float* bz, const float* Lz, const float* lbz,
                           const float* Wr, const float* br, const float* Lr, const float* lbr,
                           const float* Wh, const float* bh, const float* Lh, const float* lbh,
                           int4* __restrict__ wfrag, float* __restrict__ cvec){
  __shared__ __align__(16) float Pl[4096];   // used only by prep role; 16KB keeps
                                             // agg at its wave-cap occupancy (8 blk/CU)
  if(blockIdx.x >= AGGB){
    // -------- weight prep: Pr = W @ L_top (fp32, ascending-k order — bit-identical) --
    int m = blockIdx.x - AGGB;       // 0..5
    int g = m >> 1, half = m & 1;
    const float* W  = (g==0)?Wz:(g==1)?Wr:Wh;
    const float* L  = (g==0)?Lz:(g==1)?Lr:Lh;
    const float* bb = (g==0)?bz:(g==1)?br:bh;
    const float* lb = (g==0)?lbz:(g==1)?lbr:lbh;
    int t = threadIdx.x;
    if(half == 0){
      // stage L_top (rows 0..63 of L) into Pl
      for(int i=t; i<1024; i+=256)
        reinterpret_cast<float4*>(Pl)[i] = reinterpret_cast<const float4*>(L)[i];
      __syncthreads();
      // thread t owns row i = t>>2, cols j0..j0+15; W streamed 4 k at a time
      int i = t >> 2, j0 = (t & 3) * 16;
      float acc[16];
      #pragma unroll
      for(int q=0;q<16;q++) acc[q] = 0.f;
      for(int kb=0; kb<16; kb++){
        float4 w4 = *reinterpret_cast<const float4*>(W + i*64 + kb*4);
        const float* l0 = Pl + (kb*4)*64 + j0;
        #pragma unroll
        for(int q=0;q<16;q++) acc[q] += w4.x * l0[q];
        #pragma unroll
        for(int q=0;q<16;q++) acc[q] += w4.y * l0[64+q];
        #pragma unroll
        for(int q=0;q<16;q++) acc[q] += w4.z * l0[128+q];
        #pragma unroll
        for(int q=0;q<16;q++) acc[q] += w4.w * l0[192+q];
      }
      // bias-through-L (needs L_top still live in Pl)
      float cv = 0.f;
      if(t < 64){
        cv = lb[t];
        for(int k=0;k<64;k++) cv += bb[k]*Pl[k*64+t];
      }
      __syncthreads();
      // overwrite Pl with the product
      #pragma unroll
      for(int q=0;q<16;q++) Pl[i*64 + j0 + q] = acc[q];
      if(t < 64) cvec[g*64 + t] = cv;
      __syncthreads();
    } else {
      // H-half of L used directly
      for(int i=t; i<1024; i+=256)
        reinterpret_cast<float4*>(Pl)[i] = reinterpret_cast<const float4*>(L + 4096)[i];
      __syncthreads();
    }
    // pack to MFMA B-fragment layout (bf16)
    for(int it=t; it<512; it+=256){
      int l  = it & 63;
      int rl = it >> 6;          // s*4 + tt
      int s  = rl >> 2, tt = rl & 3;
      int k0 = s*32 + (l>>4)*8;
      int n  = tt*16 + (l&15);
      union { u16 v[8]; int4 q4; } tmp;
      #pragma unroll
      for(int j=0;j<8;j++) tmp.v[j] = f2b(Pl[(k0+j)*64 + n]);
      wfrag[m*512 + it] = tmp.q4;
    }
    return;
  }
  int wave = (blockIdx.x*blockDim.x + threadIdx.x) >> 6;
  int lane = threadIdx.x & 63;
  if(wave >= NN) return;
  int cnt = min(cursor[wave], SLOTCAP);
  float dn = dinv[wave];
  const int2* sl = slots + (size_t)wave*SLOTCAP;
  float a0=0.f, a1=0.f, a2=0.f, a3=0.f;
  int j = 0;
  for(; j+3 < cnt; j+=4){
    int2 ea = sl[j],   eb = sl[j+1];
    int2 ec = sl[j+2], ed = sl[j+3];
    ushort4 va = xt4[(size_t)ea.x*64 + lane];
    ushort4 vb = xt4[(size_t)eb.x*64 + lane];
    ushort4 vc = xt4[(size_t)ec.x*64 + lane];
    ushort4 vd = xt4[(size_t)ed.x*64 + lane];
    float wa = dinv[ea.x] * __int_as_float(ea.y) * dn;
    float wb = dinv[eb.x] * __int_as_float(eb.y) * dn;
    float wc = dinv[ec.x] * __int_as_float(ec.y) * dn;
    float wd = dinv[ed.x] * __int_as_float(ed.y) * dn;
    a0 += wa*b2f(va.x) + wb*b2f(vb.x) + wc*b2f(vc.x) + wd*b2f(vd.x);
    a1 += wa*b2f(va.y) + wb*b2f(vb.y) + wc*b2f(vc.y) + wd*b2f(vd.y);
    a2 += wa*b2f(va.z) + wb*b2f(vb.z) + wc*b2f(vc.z) + wd*b2f(vd.z);
    a3 += wa*b2f(va.w) + wb*b2f(vb.w) + wc*b2f(vc.w) + wd*b2f(vd.w);
  }
  for(; j < cnt; j++){
    int2 e = sl[j];
    float w = dinv[e.x] * __int_as_float(e.y) * dn;
    ushort4 v = xt4[(size_t)e.x*64 + lane];
    a0 += w * b2f(v.x);
    a1 += w * b2f(v.y);
    a2 += w * b2f(v.z);
    a3 += w * b2f(v.w);
  }
  int b = lane >> 4, c4 = lane & 15;
  ushort4 o; o.x=f2b(a0); o.y=f2b(a1); o.z=f2b(a2); o.w=f2b(a3);
  reinterpret_cast<ushort4*>(agg)[((size_t)b*NN + wave)*16 + c4] = o;
}

// ---------------- K3: fused GRU gate + pool partials (MFMA) ----------------
#define LDW(m,s,t) __builtin_bit_cast(s16x8, wfrag[((m)*8+(s)*4+(t))*64 + lane])

__global__ void __launch_bounds__(256, 4) gate_kernel(
    const u16* __restrict__ agg, const float* __restrict__ H,
    const int4* __restrict__ wfrag, const float* __restrict__ cvec,
    const float* __restrict__ gate_w, const float* __restrict__ gate_b,
    float* __restrict__ Hnew, float* __restrict__ ypart, float* __restrict__ dpart)
{
  __shared__ __align__(16) u16 rlds[4][1152];       // per-wave R tile, 16 rows x 72 (padded)
  __shared__ float ylds[4][64];                     // per-wave pool partials
  __shared__ float dlds[4];

  const int warp = threadIdx.x >> 6, lane = threadIdx.x & 63;
  const int mrow = lane & 15, quad = lane >> 4;
  const int bat = blockIdx.x / NBLK;
  const int blk = blockIdx.x % NBLK;
  const int tin = blk*4 + warp;           // tile within batch, 0..1251
  const bool valid = (tin < 1250);
  const int r0 = bat*NN + tin*16;         // global row (guarded by valid)

  float czv[4], crv[4], chv[4], gwv[4];
  #pragma unroll
  for(int t=0;t<4;t++){
    czv[t] = cvec[t*16+mrow];
    crv[t] = cvec[64 + t*16+mrow];
    chv[t] = cvec[128 + t*16+mrow];
    gwv[t] = gate_w[t*16+mrow];
  }
  const float gb = gate_b[0];

  f32x4 Zc[4], Rc[4], Hc[4];
  union { f32x4 v4[2]; float f[8]; } u0, u1;
  if(valid){
    const int4* ap = reinterpret_cast<const int4*>(agg + (size_t)(r0+mrow)*64);
    s16x8 a0 = __builtin_bit_cast(s16x8, ap[quad]);
    s16x8 a1 = __builtin_bit_cast(s16x8, ap[4+quad]);

    const float* Hrow = H + (size_t)(r0+mrow)*64;
    u0.v4[0] = *reinterpret_cast<const f32x4*>(Hrow + quad*8);
    u0.v4[1] = *reinterpret_cast<const f32x4*>(Hrow + quad*8 + 4);
    u1.v4[0] = *reinterpret_cast<const f32x4*>(Hrow + 32 + quad*8);
    u1.v4[1] = *reinterpret_cast<const f32x4*>(Hrow + 32 + quad*8 + 4);
    s16x8 h0, h1;
    #pragma unroll
    for(int j=0;j<8;j++){
      h0[j] = (short)f2b(u0.f[j]);
      h1[j] = (short)f2b(u1.f[j]);
    }

    #pragma unroll
    for(int t=0;t<4;t++){
      f32x4 acc = {0.f,0.f,0.f,0.f};
      acc = __builtin_amdgcn_mfma_f32_16x16x32_bf16(a0, LDW(0,0,t), acc, 0,0,0);
      acc = __builtin_amdgcn_mfma_f32_16x16x32_bf16(a1, LDW(0,1,t), acc, 0,0,0);
      acc = __builtin_amdgcn_mfma_f32_16x16x32_bf16(h0, LDW(1,0,t), acc, 0,0,0);
      acc = __builtin_amdgcn_mfma_f32_16x16x32_bf16(h1, LDW(1,1,t), acc, 0,0,0);
      Zc[t] = acc;
      f32x4 ar = {0.f,0.f,0.f,0.f};
      ar = __builtin_amdgcn_mfma_f32_16x16x32_bf16(a0, LDW(2,0,t), ar, 0,0,0);
      ar = __builtin_amdgcn_mfma_f32_16x16x32_bf16(a1, LDW(2,1,t), ar, 0,0,0);
      ar = __builtin_amdgcn_mfma_f32_16x16x32_bf16(h0, LDW(3,0,t), ar, 0,0,0);
      ar = __builtin_amdgcn_mfma_f32_16x16x32_bf16(h1, LDW(3,1,t), ar, 0,0,0);
      Rc[t] = ar;
      f32x4 ah = {0.f,0.f,0.f,0.f};
      ah = __builtin_amdgcn_mfma_f32_16x16x32_bf16(a0, LDW(4,0,t), ah, 0,0,0);
      ah = __builtin_amdgcn_mfma_f32_16x16x32_bf16(a1, LDW(4,1,t), ah, 0,0,0);
      Hc[t] = ah;
    }

    // sigmoid(R) -> LDS (C-layout write); per-warp buffer, in-wave ordering.
    #pragma unroll
    for(int t=0;t<4;t++){
      #pragma unroll
      for(int i=0;i<4;i++){
        float r = fsig(Rc[t][i] + crv[t]);
        rlds[warp][(quad*4+i)*72 + t*16 + mrow] = f2b(r);
      }
    }
    const u16* rp = &rlds[warp][mrow*72 + quad*8];
    int4 rv0 = *reinterpret_cast<const int4*>(rp);
    int4 rv1 = *reinterpret_cast<const int4*>(rp + 32);
    const u16* rv0p = reinterpret_cast<const u16*>(&rv0);
    const u16* rv1p = reinterpret_cast<const u16*>(&rv1);
    s16x8 hr0, hr1;
    #pragma unroll
    for(int j=0;j<8;j++){
      hr0[j] = (short)f2b(u0.f[j] * b2f(rv0p[j]));
      hr1[j] = (short)f2b(u1.f[j] * b2f(rv1p[j]));
    }
    #pragma unroll
    for(int t=0;t<4;t++){
      Hc[t] = __builtin_amdgcn_mfma_f32_16x16x32_bf16(hr0, LDW(5,0,t), Hc[t], 0,0,0);
      Hc[t] = __builtin_amdgcn_mfma_f32_16x16x32_bf16(hr1, LDW(5,1,t), Hc[t], 0,0,0);
    }

    // epilogue: Z, Ht, H_new, gate logits, pool partials
    float hnv[4][4];
    float ga[4] = {0.f,0.f,0.f,0.f};
    #pragma unroll
    for(int t=0;t<4;t++){
      #pragma unroll
      for(int i=0;i<4;i++){
        int row = r0 + quad*4 + i, col = t*16 + mrow;
        float z  = fsig(Zc[t][i] + czv[t]);
        float ht = ftanh(Hc[t][i] + chv[t]);
        float hv = H[(size_t)row*64 + col];
        float hn = z*hv + (1.f - z)*ht;
        Hnew[(size_t)row*64 + col] = hn;
        hnv[t][i] = hn;
        ga[i] += hn * gwv[t];
      }
    }
    #pragma unroll
    for(int i=0;i<4;i++){
      float v = ga[i];
      v += __shfl_xor(v, 1, 64);
      v += __shfl_xor(v, 2, 64);
      v += __shfl_xor(v, 4, 64);
      v += __shfl_xor(v, 8, 64);
      ga[i] = v;
    }
    float e_[4]; float dsum = 0.f;
    #pragma unroll
    for(int i=0;i<4;i++){ e_[i] = __expf(ga[i] + gb); dsum += e_[i]; }
    #pragma unroll
    for(int t=0;t<4;t++){
      float s = 0.f;
      #pragma unroll
      for(int i=0;i<4;i++) s += e_[i]*hnv[t][i];
      s += __shfl_xor(s, 16, 64);
      s += __shfl_xor(s, 32, 64);
      if(lane < 16) ylds[warp][t*16 + mrow] = s;
    }
    dsum += __shfl_xor(dsum, 16, 64);
    dsum += __shfl_xor(dsum, 32, 64);
    if(lane == 0) dlds[warp] = dsum;
  } else {
    if(lane < 16){
      #pragma unroll
      for(int t=0;t<4;t++) ylds[warp][t*16 + mrow] = 0.f;
    }
    if(lane == 0) dlds[warp] = 0.f;
  }
  __syncthreads();
  int t = threadIdx.x;
  if(t < 64){
    float s = ylds[0][t] + ylds[1][t] + ylds[2][t] + ylds[3][t];
    ypart[(size_t)blockIdx.x*64 + t] = s;
  }
  if(t == 64) dpart[blockIdx.x] = dlds[0] + dlds[1] + dlds[2] + dlds[3];
}

// ---------------- K4: head — 4 blocks, parallel partial reduce + MLP ----------
__global__ void __launch_bounds__(256) head_kernel(
    const float* __restrict__ ypart, const float* __restrict__ dpart,
    const float* W1, const float* b1,
    const float* W2, const float* b2, float* out){
  __shared__ float red[4][64];
  __shared__ float yv[64];
  __shared__ float hid[64];
  __shared__ float dshared;
  int b = blockIdx.x, t = threadIdx.x;
  int d = t & 63, q = t >> 6;
  const float* yp = ypart + (size_t)b*NBLK*64;
  float s = 0.f;
  #pragma unroll 4
  for(int k=q; k<NBLK; k+=4) s += yp[k*64 + d];
  red[q][d] = s;
  if(t < 64){
    const float* dp = dpart + b*NBLK;
    float ds = 0.f;
    for(int k=t; k<NBLK; k+=64) ds += dp[k];
    ds += __shfl_xor(ds, 1, 64);
    ds += __shfl_xor(ds, 2, 64);
    ds += __shfl_xor(ds, 4, 64);
    ds += __shfl_xor(ds, 8, 64);
    ds += __shfl_xor(ds, 16, 64);
    ds += __shfl_xor(ds, 32, 64);
    if(t == 0) dshared = ds;
  }
  __syncthreads();
  if(t < 64) yv[t] = red[0][t] + red[1][t] + red[2][t] + red[3][t];
  __syncthreads();
  if(t < 64){
    float inv = 1.f / dshared;
    float acc = b1[t];
    #pragma unroll 4
    for(int k=0;k<64;k++) acc += (yv[k]*inv) * W1[k*64+t];
    hid[t] = fmaxf(acc, 0.f);
  }
  __syncthreads();
  if(t < 32){
    float a2 = b2[t];
    #pragma unroll 4
    for(int d2=0; d2<64; d2++) a2 += hid[d2] * W2[d2*32+t];
    out[b*32+t] = a2;
  }
}

// ---------------- launch ----------------
extern "C" void kernel_launch(void* const* d_in, const int* in_sizes, int n_in,
                              void* d_out, int out_size, void* d_ws, size_t ws_size,
                              hipStream_t stream) {
  const float* x   = (const float*)d_in[0];
  const int*   ei  = (const int*)d_in[1];
  const float* ew  = (const float*)d_in[2];
  const float* H   = (const float*)d_in[3];
  const float* Wz = (const float*)d_in[4],  *bz = (const float*)d_in[5];
  const float* Wr = (const float*)d_in[6],  *br = (const float*)d_in[7];
  const float* Wh = (const float*)d_in[8],  *bh = (const float*)d_in[9];
  const float* Lz = (const float*)d_in[10], *lbz = (const float*)d_in[11];
  const float* Lr = (const float*)d_in[12], *lbr = (const float*)d_in[13];
  const float* Lh = (const float*)d_in[14], *lbh = (const float*)d_in[15];
  const float* gw = (const float*)d_in[16], *gbp = (const float*)d_in[17];
  const float* W1 = (const float*)d_in[18], *b1 = (const float*)d_in[19];
  const float* W2 = (const float*)d_in[20], *b2 = (const float*)d_in[21];

  float* y_out    = (float*)d_out;
  float* Hnew_out = (float*)d_out + 128;

  char* ws = (char*)d_ws;
  size_t off = 0;
  auto alloc = [&](size_t bytes)->char*{
    off = (off + 255) & ~(size_t)255;
    char* p = ws + off; off += bytes; return p;
  };
  float*   dinv     = (float*)alloc(NN*4);
  int*     cursor   = (int*)  alloc(NN*4);
  int2*    slots    = (int2*) alloc((size_t)NN*SLOTCAP*8);
  ushort4* xt4      = (ushort4*)alloc((size_t)NN*256*2);
  u16*     agg      = (u16*)  alloc((size_t)ROWS*64*2);
  int4*    wfrag    = (int4*) alloc(3072*16);
  float*   cvec     = (float*)alloc(192*4);
  float*   ypart    = (float*)alloc((size_t)NB*NBLK*64*4);
  float*   dpart    = (float*)alloc((size_t)NB*NBLK*4);
  (void)ws_size; (void)n_in; (void)in_sizes; (void)out_size;

  // pre-zero cursor only (dinv is fully overwritten by degsum_kernel)
  hipMemsetAsync(cursor, 0, NN*4, stream);

  setup_kernel<<<FSBLK + XTBLK, 256, 0, stream>>>(
      x, xt4, ei, ew, cursor, slots);
  degsum_kernel<<<FSBLK, 256, 0, stream>>>(cursor, slots, dinv);
  agg_kernel<<<AGGB + PREPB, 256, 0, stream>>>(
      xt4, dinv, cursor, slots, agg,
      Wz,bz,Lz,lbz, Wr,br,Lr,lbr, Wh,bh,Lh,lbh, wfrag, cvec);
  gate_kernel<<<NB*NBLK, 256, 0, stream>>>(agg, H, wfrag, cvec, gw, gbp, Hnew_out, ypart, dpart);
  head_kernel<<<4, 256, 0, stream>>>(ypart, dpart, W1, b1, W2, b2, y_out);
}

// Round 8
// 209.334 us; speedup vs baseline: 1.2017x; 1.0166x over previous
//
#include <hip/hip_runtime.h>
#include <hip/hip_bf16.h>

typedef unsigned short u16;
typedef float f32x4 __attribute__((ext_vector_type(4)));
typedef short s16x8 __attribute__((ext_vector_type(8)));

#define NB 4
#define NN 20000
#define NE 320000
#define ROWS (NB*NN)          // 80000
#define NBLK 313              // gate blocks per batch (313*4 waves >= 1250 tiles)
#define SLOTCAP 64            // max degree capacity (Poisson(16): P(>64) ~ 1e-20)
#define XTBLK 5000            // xt role blocks in setup
#define SCB 1024              // scatter blocks (multiple of 8; 8 XCD-bins x 128)
#define DRANGE 2500           // NN/8 dst nodes per XCD bin
#define FSBLK 1250            // degsum blocks (1250*256/16 == NN)
#define AGGB 5000             // agg role blocks ((NN+3)/4); prep blocks appended after
#define PREPB 6               // weight-prep role blocks (in agg_kernel)

__device__ __forceinline__ float b2f(u16 u){
  union{unsigned int i; float f;} v; v.i = ((unsigned int)u)<<16; return v.f;
}
__device__ __forceinline__ u16 f2b(float f){
  __hip_bfloat16 h = __float2bfloat16(f);
  return __builtin_bit_cast(u16, h);
}

// fast sigmoid/tanh: v_rcp + v_exp (rel err ~1e-6; tolerance budget is bf16-level)
__device__ __forceinline__ float fsig(float x){
  return __builtin_amdgcn_rcpf(1.f + __expf(-x));
}
__device__ __forceinline__ float ftanh(float x){
  // 1 - 2/(e^{2x}+1): x->+inf => 1, x->-inf => -1 (no NaN at saturation)
  return 1.f - 2.f*__builtin_amdgcn_rcpf(__expf(2.f*x) + 1.f);
}

// ---------------- K1: setup — XCD-binned edge scatter FIRST (blocks 0..SCB-1),
//                   xt transpose after. Scatter group g = bid&7 (round-robins
//                   XCDs) owns dst range [g*2500,(g+1)*2500): its 1.28MB slot
//                   region stays resident in ONE XCD's L2, so each slot line
//                   merges all its ~8 entries before a single writeback
//                   (random-line RMW traffic was the measured wall). ----------
__global__ void __launch_bounds__(256, 8) setup_kernel(
    const float* __restrict__ x, ushort4* __restrict__ xt4,
    const int* __restrict__ ei, const float* __restrict__ ew,
    int* __restrict__ cursor, int2* __restrict__ slots){
  int bid = blockIdx.x;
  if(bid < SCB){
    // -------- edge scatter, dst-filtered by XCD bin --------
    int g  = bid & 7;                  // XCD bin (dispatch round-robin heuristic;
                                       // correctness does not depend on it)
    int wb = bid >> 3;                 // 0..127 within group
    int lo = g*DRANGE, hi = lo + DRANGE;
    for(int e = wb*256 + threadIdx.x; e < NE; e += (SCB/8)*256){
      int d = ei[NE + e];              // dst stream: 8x replicated reads, L3-served
      if(d >= lo && d < hi){
        int s = ei[e];
        float w = ew[e];
        int p = atomicAdd(&cursor[d], 1);
        if(p < SLOTCAP){
          int2 ent; ent.x = s; ent.y = __float_as_int(w);
          slots[d*SLOTCAP + p] = ent;
        }
      }
    }
  } else {
    // -------- xt transpose: pure streaming, backfills behind scatter --------
    int t = (bid - SCB)*256 + threadIdx.x;   // 0 .. NB*NN*16-1
    int b = t / (NN*16);
    int rem = t - b*(NN*16);
    int n = rem >> 4;
    int c4 = rem & 15;
    float4 v = reinterpret_cast<const float4*>(x)[t];
    ushort4 o; o.x=f2b(v.x); o.y=f2b(v.y); o.z=f2b(v.z); o.w=f2b(v.w);
    xt4[(size_t)n*64 + b*16 + c4] = o;
  }
}

__device__ __forceinline__ float dinvf(float d){
  return (d > 0.f) ? rsqrtf(fmaxf(d, 1e-12f)) : 0.f;
}

// ---------------- K1b: degsum — dinv[n] = rsqrt(sum of stored weights).
//                   Quarter-wave per node; slots are L2/L3-hot. -------------
__global__ void __launch_bounds__(256, 8) degsum_kernel(
    const int* __restrict__ cursor, const int2* __restrict__ slots,
    float* __restrict__ dinv){
  int node = (blockIdx.x*256 + threadIdx.x) >> 4;
  int sub  = threadIdx.x & 15;
  if(node >= NN) return;
  int cnt = min(cursor[node], SLOTCAP);
  const int2* sl = slots + (size_t)node*SLOTCAP;
  float s = 0.f;
  for(int j=sub; j<cnt; j+=16) s += __int_as_float(sl[j].y);
  s += __shfl_xor(s, 1, 16);
  s += __shfl_xor(s, 2, 16);
  s += __shfl_xor(s, 4, 16);
  s += __shfl_xor(s, 8, 16);
  if(sub == 0) dinv[node] = dinvf(s);
}

// ---------------- K2: per-node aggregation (wave per node, 4x unrolled) +
//                   weight-prep role in 6 tail blocks. ----------------------
__global__ void agg_kernel(const ushort4* __restrict__ xt4, const float* __restrict__ dinv,
                           const int* __restrict__ cursor, const int2* __restrict__ slots,
                           u16* __restrict__ agg,
                           const float* Wz, const float* bz, const float* Lz, const float* lbz,
                           const float* Wr, const float* br, const float* Lr, const float* lbr,
                           const float* Wh, const float* bh, const float* Lh, const float* lbh,
                           int4* __restrict__ wfrag, float* __restrict__ cvec){
  __shared__ __align__(16) float Pl[4096];   // used only by prep role; 16KB keeps
                                             // agg at its wave-cap occupancy (8 blk/CU)
  if(blockIdx.x >= AGGB){
    // -------- weight prep: Pr = W @ L_top (fp32, ascending-k order — bit-identical) --
    int m = blockIdx.x - AGGB;       // 0..5
    int g = m >> 1, half = m & 1;
    const float* W  = (g==0)?Wz:(g==1)?Wr:Wh;
    const float* L  = (g==0)?Lz:(g==1)?Lr:Lh;
    const float* bb = (g==0)?bz:(g==1)?br:bh;
    const float* lb = (g==0)?lbz:(g==1)?lbr:lbh;
    int t = threadIdx.x;
    if(half == 0){
      // stage L_top (rows 0..63 of L) into Pl
      for(int i=t; i<1024; i+=256)
        reinterpret_cast<float4*>(Pl)[i] = reinterpret_cast<const float4*>(L)[i];
      __syncthreads();
      // thread t owns row i = t>>2, cols j0..j0+15; W streamed 4 k at a time
      int i = t >> 2, j0 = (t & 3) * 16;
      float acc[16];
      #pragma unroll
      for(int q=0;q<16;q++) acc[q] = 0.f;
      for(int kb=0; kb<16; kb++){
        float4 w4 = *reinterpret_cast<const float4*>(W + i*64 + kb*4);
        const float* l0 = Pl + (kb*4)*64 + j0;
        #pragma unroll
        for(int q=0;q<16;q++) acc[q] += w4.x * l0[q];
        #pragma unroll
        for(int q=0;q<16;q++) acc[q] += w4.y * l0[64+q];
        #pragma unroll
        for(int q=0;q<16;q++) acc[q] += w4.z * l0[128+q];
        #pragma unroll
        for(int q=0;q<16;q++) acc[q] += w4.w * l0[192+q];
      }
      // bias-through-L (needs L_top still live in Pl)
      float cv = 0.f;
      if(t < 64){
        cv = lb[t];
        for(int k=0;k<64;k++) cv += bb[k]*Pl[k*64+t];
      }
      __syncthreads();
      // overwrite Pl with the product
      #pragma unroll
      for(int q=0;q<16;q++) Pl[i*64 + j0 + q] = acc[q];
      if(t < 64) cvec[g*64 + t] = cv;
      __syncthreads();
    } else {
      // H-half of L used directly
      for(int i=t; i<1024; i+=256)
        reinterpret_cast<float4*>(Pl)[i] = reinterpret_cast<const float4*>(L + 4096)[i];
      __syncthreads();
    }
    // pack to MFMA B-fragment layout (bf16)
    for(int it=t; it<512; it+=256){
      int l  = it & 63;
      int rl = it >> 6;          // s*4 + tt
      int s  = rl >> 2, tt = rl & 3;
      int k0 = s*32 + (l>>4)*8;
      int n  = tt*16 + (l&15);
      union { u16 v[8]; int4 q4; } tmp;
      #pragma unroll
      for(int j=0;j<8;j++) tmp.v[j] = f2b(Pl[(k0+j)*64 + n]);
      wfrag[m*512 + it] = tmp.q4;
    }
    return;
  }
  int wave = (blockIdx.x*blockDim.x + threadIdx.x) >> 6;
  int lane = threadIdx.x & 63;
  if(wave >= NN) return;
  int cnt = min(cursor[wave], SLOTCAP);
  float dn = dinv[wave];
  const int2* sl = slots + (size_t)wave*SLOTCAP;
  float a0=0.f, a1=0.f, a2=0.f, a3=0.f;
  int j = 0;
  for(; j+3 < cnt; j+=4){
    int2 ea = sl[j],   eb = sl[j+1];
    int2 ec = sl[j+2], ed = sl[j+3];
    ushort4 va = xt4[(size_t)ea.x*64 + lane];
    ushort4 vb = xt4[(size_t)eb.x*64 + lane];
    ushort4 vc = xt4[(size_t)ec.x*64 + lane];
    ushort4 vd = xt4[(size_t)ed.x*64 + lane];
    float wa = dinv[ea.x] * __int_as_float(ea.y) * dn;
    float wb = dinv[eb.x] * __int_as_float(eb.y) * dn;
    float wc = dinv[ec.x] * __int_as_float(ec.y) * dn;
    float wd = dinv[ed.x] * __int_as_float(ed.y) * dn;
    a0 += wa*b2f(va.x) + wb*b2f(vb.x) + wc*b2f(vc.x) + wd*b2f(vd.x);
    a1 += wa*b2f(va.y) + wb*b2f(vb.y) + wc*b2f(vc.y) + wd*b2f(vd.y);
    a2 += wa*b2f(va.z) + wb*b2f(vb.z) + wc*b2f(vc.z) + wd*b2f(vd.z);
    a3 += wa*b2f(va.w) + wb*b2f(vb.w) + wc*b2f(vc.w) + wd*b2f(vd.w);
  }
  for(; j < cnt; j++){
    int2 e = sl[j];
    float w = dinv[e.x] * __int_as_float(e.y) * dn;
    ushort4 v = xt4[(size_t)e.x*64 + lane];
    a0 += w * b2f(v.x);
    a1 += w * b2f(v.y);
    a2 += w * b2f(v.z);
    a3 += w * b2f(v.w);
  }
  int b = lane >> 4, c4 = lane & 15;
  ushort4 o; o.x=f2b(a0); o.y=f2b(a1); o.z=f2b(a2); o.w=f2b(a3);
  reinterpret_cast<ushort4*>(agg)[((size_t)b*NN + wave)*16 + c4] = o;
}

// ---------------- K3: fused GRU gate + pool partials (MFMA) ----------------
#define LDW(m,s,t) __builtin_bit_cast(s16x8, wfrag[((m)*8+(s)*4+(t))*64 + lane])

__global__ void __launch_bounds__(256, 4) gate_kernel(
    const u16* __restrict__ agg, const float* __restrict__ H,
    const int4* __restrict__ wfrag, const float* __restrict__ cvec,
    const float* __restrict__ gate_w, const float* __restrict__ gate_b,
    float* __restrict__ Hnew, float* __restrict__ ypart, float* __restrict__ dpart)
{
  __shared__ __align__(16) u16 rlds[4][1152];       // per-wave R tile, 16 rows x 72 (padded)
  __shared__ float ylds[4][64];                     // per-wave pool partials
  __shared__ float dlds[4];

  const int warp = threadIdx.x >> 6, lane = threadIdx.x & 63;
  const int mrow = lane & 15, quad = lane >> 4;
  const int bat = blockIdx.x / NBLK;
  const int blk = blockIdx.x % NBLK;
  const int tin = blk*4 + warp;           // tile within batch, 0..1251
  const bool valid = (tin < 1250);
  const int r0 = bat*NN + tin*16;         // global row (guarded by valid)

  float czv[4], crv[4], chv[4], gwv[4];
  #pragma unroll
  for(int t=0;t<4;t++){
    czv[t] = cvec[t*16+mrow];
    crv[t] = cvec[64 + t*16+mrow];
    chv[t] = cvec[128 + t*16+mrow];
    gwv[t] = gate_w[t*16+mrow];
  }
  const float gb = gate_b[0];

  f32x4 Zc[4], Rc[4], Hc[4];
  union { f32x4 v4[2]; float f[8]; } u0, u1;
  if(valid){
    const int4* ap = reinterpret_cast<const int4*>(agg + (size_t)(r0+mrow)*64);
    s16x8 a0 = __builtin_bit_cast(s16x8, ap[quad]);
    s16x8 a1 = __builtin_bit_cast(s16x8, ap[4+quad]);

    const float* Hrow = H + (size_t)(r0+mrow)*64;
    u0.v4[0] = *reinterpret_cast<const f32x4*>(Hrow + quad*8);
    u0.v4[1] = *reinterpret_cast<const f32x4*>(Hrow + quad*8 + 4);
    u1.v4[0] = *reinterpret_cast<const f32x4*>(Hrow + 32 + quad*8);
    u1.v4[1] = *reinterpret_cast<const f32x4*>(Hrow + 32 + quad*8 + 4);
    s16x8 h0, h1;
    #pragma unroll
    for(int j=0;j<8;j++){
      h0[j] = (short)f2b(u0.f[j]);
      h1[j] = (short)f2b(u1.f[j]);
    }

    #pragma unroll
    for(int t=0;t<4;t++){
      f32x4 acc = {0.f,0.f,0.f,0.f};
      acc = __builtin_amdgcn_mfma_f32_16x16x32_bf16(a0, LDW(0,0,t), acc, 0,0,0);
      acc = __builtin_amdgcn_mfma_f32_16x16x32_bf16(a1, LDW(0,1,t), acc, 0,0,0);
      acc = __builtin_amdgcn_mfma_f32_16x16x32_bf16(h0, LDW(1,0,t), acc, 0,0,0);
      acc = __builtin_amdgcn_mfma_f32_16x16x32_bf16(h1, LDW(1,1,t), acc, 0,0,0);
      Zc[t] = acc;
      f32x4 ar = {0.f,0.f,0.f,0.f};
      ar = __builtin_amdgcn_mfma_f32_16x16x32_bf16(a0, LDW(2,0,t), ar, 0,0,0);
      ar = __builtin_amdgcn_mfma_f32_16x16x32_bf16(a1, LDW(2,1,t), ar, 0,0,0);
      ar = __builtin_amdgcn_mfma_f32_16x16x32_bf16(h0, LDW(3,0,t), ar, 0,0,0);
      ar = __builtin_amdgcn_mfma_f32_16x16x32_bf16(h1, LDW(3,1,t), ar, 0,0,0);
      Rc[t] = ar;
      f32x4 ah = {0.f,0.f,0.f,0.f};
      ah = __builtin_amdgcn_mfma_f32_16x16x32_bf16(a0, LDW(4,0,t), ah, 0,0,0);
      ah = __builtin_amdgcn_mfma_f32_16x16x32_bf16(a1, LDW(4,1,t), ah, 0,0,0);
      Hc[t] = ah;
    }

    // sigmoid(R) -> LDS (C-layout write); per-warp buffer, in-wave ordering.
    #pragma unroll
    for(int t=0;t<4;t++){
      #pragma unroll
      for(int i=0;i<4;i++){
        float r = fsig(Rc[t][i] + crv[t]);
        rlds[warp][(quad*4+i)*72 + t*16 + mrow] = f2b(r);
      }
    }
    const u16* rp = &rlds[warp][mrow*72 + quad*8];
    int4 rv0 = *reinterpret_cast<const int4*>(rp);
    int4 rv1 = *reinterpret_cast<const int4*>(rp + 32);
    const u16* rv0p = reinterpret_cast<const u16*>(&rv0);
    const u16* rv1p = reinterpret_cast<const u16*>(&rv1);
    s16x8 hr0, hr1;
    #pragma unroll
    for(int j=0;j<8;j++){
      hr0[j] = (short)f2b(u0.f[j] * b2f(rv0p[j]));
      hr1[j] = (short)f2b(u1.f[j] * b2f(rv1p[j]));
    }
    #pragma unroll
    for(int t=0;t<4;t++){
      Hc[t] = __builtin_amdgcn_mfma_f32_16x16x32_bf16(hr0, LDW(5,0,t), Hc[t], 0,0,0);
      Hc[t] = __builtin_amdgcn_mfma_f32_16x16x32_bf16(hr1, LDW(5,1,t), Hc[t], 0,0,0);
    }

    // epilogue: Z, Ht, H_new, gate logits, pool partials
    float hnv[4][4];
    float ga[4] = {0.f,0.f,0.f,0.f};
    #pragma unroll
    for(int t=0;t<4;t++){
      #pragma unroll
      for(int i=0;i<4;i++){
        int row = r0 + quad*4 + i, col = t*16 + mrow;
        float z  = fsig(Zc[t][i] + czv[t]);
        float ht = ftanh(Hc[t][i] + chv[t]);
        float hv = H[(size_t)row*64 + col];
        float hn = z*hv + (1.f - z)*ht;
        Hnew[(size_t)row*64 + col] = hn;
        hnv[t][i] = hn;
        ga[i] += hn * gwv[t];
      }
    }
    #pragma unroll
    for(int i=0;i<4;i++){
      float v = ga[i];
      v += __shfl_xor(v, 1, 64);
      v += __shfl_xor(v, 2, 64);
      v += __shfl_xor(v, 4, 64);
      v += __shfl_xor(v, 8, 64);
      ga[i] = v;
    }
    float e_[4]; float dsum = 0.f;
    #pragma unroll
    for(int i=0;i<4;i++){ e_[i] = __expf(ga[i] + gb); dsum += e_[i]; }
    #pragma unroll
    for(int t=0;t<4;t++){
      float s = 0.f;
      #pragma unroll
      for(int i=0;i<4;i++) s += e_[i]*hnv[t][i];
      s += __shfl_xor(s, 16, 64);
      s += __shfl_xor(s, 32, 64);
      if(lane < 16) ylds[warp][t*16 + mrow] = s;
    }
    dsum += __shfl_xor(dsum, 16, 64);
    dsum += __shfl_xor(dsum, 32, 64);
    if(lane == 0) dlds[warp] = dsum;
  } else {
    if(lane < 16){
      #pragma unroll
      for(int t=0;t<4;t++) ylds[warp][t*16 + mrow] = 0.f;
    }
    if(lane == 0) dlds[warp] = 0.f;
  }
  __syncthreads();
  int t = threadIdx.x;
  if(t < 64){
    float s = ylds[0][t] + ylds[1][t] + ylds[2][t] + ylds[3][t];
    ypart[(size_t)blockIdx.x*64 + t] = s;
  }
  if(t == 64) dpart[blockIdx.x] = dlds[0] + dlds[1] + dlds[2] + dlds[3];
}

// ---------------- K4: head — 4 blocks, parallel partial reduce + MLP ----------
__global__ void __launch_bounds__(256) head_kernel(
    const float* __restrict__ ypart, const float* __restrict__ dpart,
    const float* W1, const float* b1,
    const float* W2, const float* b2, float* out){
  __shared__ float red[4][64];
  __shared__ float yv[64];
  __shared__ float hid[64];
  __shared__ float dshared;
  int b = blockIdx.x, t = threadIdx.x;
  int d = t & 63, q = t >> 6;
  const float* yp = ypart + (size_t)b*NBLK*64;
  float s = 0.f;
  #pragma unroll 4
  for(int k=q; k<NBLK; k+=4) s += yp[k*64 + d];
  red[q][d] = s;
  if(t < 64){
    const float* dp = dpart + b*NBLK;
    float ds = 0.f;
    for(int k=t; k<NBLK; k+=64) ds += dp[k];
    ds += __shfl_xor(ds, 1, 64);
    ds += __shfl_xor(ds, 2, 64);
    ds += __shfl_xor(ds, 4, 64);
    ds += __shfl_xor(ds, 8, 64);
    ds += __shfl_xor(ds, 16, 64);
    ds += __shfl_xor(ds, 32, 64);
    if(t == 0) dshared = ds;
  }
  __syncthreads();
  if(t < 64) yv[t] = red[0][t] + red[1][t] + red[2][t] + red[3][t];
  __syncthreads();
  if(t < 64){
    float inv = 1.f / dshared;
    float acc = b1[t];
    #pragma unroll 4
    for(int k=0;k<64;k++) acc += (yv[k]*inv) * W1[k*64+t];
    hid[t] = fmaxf(acc, 0.f);
  }
  __syncthreads();
  if(t < 32){
    float a2 = b2[t];
    #pragma unroll 4
    for(int d2=0; d2<64; d2++) a2 += hid[d2] * W2[d2*32+t];
    out[b*32+t] = a2;
  }
}

// ---------------- launch ----------------
extern "C" void kernel_launch(void* const* d_in, const int* in_sizes, int n_in,
                              void* d_out, int out_size, void* d_ws, size_t ws_size,
                              hipStream_t stream) {
  const float* x   = (const float*)d_in[0];
  const int*   ei  = (const int*)d_in[1];
  const float* ew  = (const float*)d_in[2];
  const float* H   = (const float*)d_in[3];
  const float* Wz = (const float*)d_in[4],  *bz = (const float*)d_in[5];
  const float* Wr = (const float*)d_in[6],  *br = (const float*)d_in[7];
  const float* Wh = (const float*)d_in[8],  *bh = (const float*)d_in[9];
  const float* Lz = (const float*)d_in[10], *lbz = (const float*)d_in[11];
  const float* Lr = (const float*)d_in[12], *lbr = (const float*)d_in[13];
  const float* Lh = (const float*)d_in[14], *lbh = (const float*)d_in[15];
  const float* gw = (const float*)d_in[16], *gbp = (const float*)d_in[17];
  const float* W1 = (const float*)d_in[18], *b1 = (const float*)d_in[19];
  const float* W2 = (const float*)d_in[20], *b2 = (const float*)d_in[21];

  float* y_out    = (float*)d_out;
  float* Hnew_out = (float*)d_out + 128;

  char* ws = (char*)d_ws;
  size_t off = 0;
  auto alloc = [&](size_t bytes)->char*{
    off = (off + 255) & ~(size_t)255;
    char* p = ws + off; off += bytes; return p;
  };
  float*   dinv     = (float*)alloc(NN*4);
  int*     cursor   = (int*)  alloc(NN*4);
  int2*    slots    = (int2*) alloc((size_t)NN*SLOTCAP*8);
  ushort4* xt4      = (ushort4*)alloc((size_t)NN*256*2);
  u16*     agg      = (u16*)  alloc((size_t)ROWS*64*2);
  int4*    wfrag    = (int4*) alloc(3072*16);
  float*   cvec     = (float*)alloc(192*4);
  float*   ypart    = (float*)alloc((size_t)NB*NBLK*64*4);
  float*   dpart    = (float*)alloc((size_t)NB*NBLK*4);
  (void)ws_size; (void)n_in; (void)in_sizes; (void)out_size;

  // pre-zero cursor only (dinv is fully overwritten by degsum_kernel)
  (void)hipMemsetAsync(cursor, 0, NN*4, stream);

  setup_kernel<<<SCB + XTBLK, 256, 0, stream>>>(
      x, xt4, ei, ew, cursor, slots);
  degsum_kernel<<<FSBLK, 256, 0, stream>>>(cursor, slots, dinv);
  agg_kernel<<<AGGB + PREPB, 256, 0, stream>>>(
      xt4, dinv, cursor, slots, agg,
      Wz,bz,Lz,lbz, Wr,br,Lr,lbr, Wh,bh,Lh,lbh, wfrag, cvec);
  gate_kernel<<<NB*NBLK, 256, 0, stream>>>(agg, H, wfrag, cvec, gw, gbp, Hnew_out, ypart, dpart);
  head_kernel<<<4, 256, 0, stream>>>(ypart, dpart, W1, b1, W2, b2, y_out);
}